// Round 2
// baseline (408.694 us; speedup 1.0000x reference)
//
#include <hip/hip_runtime.h>
#include <math.h>

#define BB 128
#define SS 1024
#define EE 2048
#define HH 300
#define AA 5
#define CC 3
#define NB 8          // softmax partial blocks per sample
#define PSTRIDE 304   // partial record: 300 acc + l + m (padded)
#define EMAX 2049     // worst case: all E edges into one node + self

// ---------------- ws layout (floats) ----------------
// deg  [B*S] | qbuf [B*H] | part [B*NB*PSTRIDE] | span [B*H] | syn [B*H]
// total ~2.23 MB — initialized every call (harness re-poisons ws with 0xAA)

__global__ void k_init(float* deg, float* syn) {
    int gid = blockIdx.x * blockDim.x + threadIdx.x;
    if (gid < BB * SS) deg[gid] = 1.0f;     // self-loop contributes +1
    if (gid < BB * HH) syn[gid] = 0.0f;
}

__global__ void k_deg(const int* __restrict__ eidx, const float* __restrict__ ew,
                      float* __restrict__ deg) {
    int gid = blockIdx.x * blockDim.x + threadIdx.x;
    if (gid >= BB * EE) return;
    int b = gid >> 11;            // E = 2048
    int e = gid & (EE - 1);
    int d = eidx[(size_t)b * 2 * EE + EE + e];
    atomicAdd(&deg[b * SS + d], ew[(size_t)b * EE + e]);
}

// q = (mean of h at aspect positions) @ W_span + b_span
__global__ __launch_bounds__(320) void k_q(const float* __restrict__ h, const int* __restrict__ ap,
                                           const float* __restrict__ W_span, const float* __restrict__ b_span,
                                           float* __restrict__ qbuf) {
    int b = blockIdx.x;
    __shared__ float av[HH];
    const float* hb = h + (size_t)b * SS * HH;
    for (int j = threadIdx.x; j < HH; j += blockDim.x) {
        float s = 0.f;
        for (int a = 0; a < AA; ++a) s += hb[(size_t)ap[b * AA + a] * HH + j];
        av[j] = s * (1.0f / AA);
    }
    __syncthreads();
    for (int j = threadIdx.x; j < HH; j += blockDim.x) {
        float acc = b_span[j];
        for (int i = 0; i < HH; ++i) acc += av[i] * W_span[i * HH + j];
        qbuf[b * HH + j] = acc;
    }
}

// online-softmax partials: one pass over h. Each block: 128 rows, 4 waves x 32 rows.
__global__ __launch_bounds__(256) void k_span_part(const float* __restrict__ h,
                                                   const float* __restrict__ qbuf,
                                                   float* __restrict__ part) {
    int b = blockIdx.x / NB, nb = blockIdx.x % NB;
    int tid = threadIdx.x, lane = tid & 63, w = tid >> 6;
    const float* hb = h + (size_t)b * SS * HH;
    const float* qb = qbuf + b * HH;
    float qr[5];
#pragma unroll
    for (int k = 0; k < 5; ++k) { int idx = lane + 64 * k; qr[k] = (idx < HH) ? qb[idx] : 0.f; }
    float m = -INFINITY, l = 0.f;
    float acc[5] = {0.f, 0.f, 0.f, 0.f, 0.f};
    int row0 = nb * (SS / NB) + w * 32;
    for (int t = 0; t < 32; ++t) {
        const float* hr = hb + (size_t)(row0 + t) * HH;
        float hv[5]; float pd = 0.f;
#pragma unroll
        for (int k = 0; k < 5; ++k) {
            int idx = lane + 64 * k;
            hv[k] = (idx < HH) ? hr[idx] : 0.f;
            pd += hv[k] * qr[k];
        }
#pragma unroll
        for (int off = 32; off > 0; off >>= 1) pd += __shfl_xor(pd, off, 64);
        float mn = fmaxf(m, pd);
        float sc = __expf(m - mn);     // exp(-inf)=0 handles first row
        float p  = __expf(pd - mn);
        l = l * sc + p;
#pragma unroll
        for (int k = 0; k < 5; ++k) acc[k] = acc[k] * sc + p * hv[k];
        m = mn;
    }
    __shared__ float sm[4], sl[4], sacc[4][PSTRIDE];
#pragma unroll
    for (int k = 0; k < 5; ++k) { int idx = lane + 64 * k; if (idx < HH) sacc[w][idx] = acc[k]; }
    if (lane == 0) { sm[w] = m; sl[w] = l; }
    __syncthreads();
    float M = fmaxf(fmaxf(sm[0], sm[1]), fmaxf(sm[2], sm[3]));
    float* pb = part + ((size_t)b * NB + nb) * PSTRIDE;
    for (int j = tid; j < HH; j += 256) {
        float s = 0.f;
#pragma unroll
        for (int ww = 0; ww < 4; ++ww) s += sacc[ww][j] * __expf(sm[ww] - M);
        pb[j] = s;
    }
    if (tid == 0) {
        float L = 0.f;
        for (int ww = 0; ww < 4; ++ww) L += sl[ww] * __expf(sm[ww] - M);
        pb[300] = L; pb[301] = M;
    }
}

__global__ __launch_bounds__(256) void k_span_final(const float* __restrict__ part,
                                                    float* __restrict__ span) {
    int b = blockIdx.x; int tid = threadIdx.x;
    const float* pb = part + (size_t)b * NB * PSTRIDE;
    float M = -INFINITY;
    for (int nb = 0; nb < NB; ++nb) M = fmaxf(M, pb[nb * PSTRIDE + 301]);
    float L = 0.f;
    for (int nb = 0; nb < NB; ++nb) L += pb[nb * PSTRIDE + 300] * __expf(pb[nb * PSTRIDE + 301] - M);
    float invL = 1.0f / L;
    for (int j = tid; j < HH; j += blockDim.x) {
        float s = 0.f;
        for (int nb = 0; nb < NB; ++nb) s += pb[nb * PSTRIDE + j] * __expf(pb[nb * PSTRIDE + 301] - M);
        span[b * HH + j] = s * invL;
    }
}

// Output-sparse 2-layer GCN: compute x2 only at aspect rows via the backward cone.
// Key identity: conv(x)(r) = b + (c_self*x[r] + sum_e norm[e]*x[src[e]]) @ W  (sum rows BEFORE matvec)
__global__ __launch_bounds__(320) void k_syn(const float* __restrict__ h, const int* __restrict__ eidx,
                                             const float* __restrict__ ew, const int* __restrict__ ap,
                                             const float* __restrict__ W1, const float* __restrict__ b1,
                                             const float* __restrict__ W2, const float* __restrict__ b2,
                                             const float* __restrict__ deg, float* __restrict__ syn) {
    int b = blockIdx.x / AA, a = blockIdx.x % AA;
    int tid = threadIdx.x;
    const int* srcA = eidx + (size_t)b * 2 * EE;
    const int* dstA = srcA + EE;
    const float* ewb  = ew + (size_t)b * EE;
    const float* hb   = h + (size_t)b * SS * HH;
    const float* degb = deg + (size_t)b * SS;
    __shared__ float z[HH], svec[HH];
    __shared__ float lco_c[EMAX]; __shared__ int lco_r[EMAX];
    __shared__ float lci_c[EMAX]; __shared__ int lci_r[EMAX];
    __shared__ int lco_cnt, lci_cnt;

    int pos = ap[b * AA + a];
    for (int j = tid; j < HH; j += blockDim.x) z[j] = 0.f;
    if (tid == 0) { lco_cnt = 1; lco_c[0] = 1.0f / degb[pos]; lco_r[0] = pos; }
    __syncthreads();
    float dip = rsqrtf(degb[pos]);
    for (int e = tid; e < EE; e += blockDim.x) {
        if (dstA[e] == pos) {
            int k = atomicAdd(&lco_cnt, 1);
            if (k < EMAX) { lco_c[k] = rsqrtf(degb[srcA[e]]) * ewb[e] * dip; lco_r[k] = srcA[e]; }
        }
    }
    __syncthreads();
    int nc = lco_cnt; if (nc > EMAX) nc = EMAX;

    for (int ci = 0; ci < nc; ++ci) {
        int r = lco_r[ci]; float cr = lco_c[ci];
        if (tid == 0) { lci_cnt = 1; lci_c[0] = 1.0f / degb[r]; lci_r[0] = r; }
        __syncthreads();
        float dir = rsqrtf(degb[r]);
        for (int e = tid; e < EE; e += blockDim.x) {
            if (dstA[e] == r) {
                int k = atomicAdd(&lci_cnt, 1);
                if (k < EMAX) { lci_c[k] = rsqrtf(degb[srcA[e]]) * ewb[e] * dir; lci_r[k] = srcA[e]; }
            }
        }
        __syncthreads();
        int ni = lci_cnt; if (ni > EMAX) ni = EMAX;
        // svec = weighted sum of h rows feeding x1[r]
        for (int j = tid; j < HH; j += blockDim.x) {
            float s = 0.f;
            for (int k = 0; k < ni; ++k) s += lci_c[k] * hb[(size_t)lci_r[k] * HH + j];
            svec[j] = s;
        }
        __syncthreads();
        // z += cr * relu(b1 + svec @ W1)
        for (int j = tid; j < HH; j += blockDim.x) {
            float acc2 = b1[j];
            for (int i = 0; i < HH; ++i) acc2 += svec[i] * W1[i * HH + j];
            z[j] += cr * fmaxf(acc2, 0.f);
        }
        __syncthreads();
    }
    // out2 = b2 + z @ W2 ; syn += out2 / A
    for (int j = tid; j < HH; j += blockDim.x) {
        float acc2 = b2[j];
        for (int i = 0; i < HH; ++i) acc2 += z[i] * W2[i * HH + j];
        atomicAdd(&syn[b * HH + j], acc2 * (1.0f / AA));
    }
}

__global__ __launch_bounds__(320) void k_head(const float* __restrict__ span, const float* __restrict__ syn,
                                              const float* __restrict__ W_gate, const float* __restrict__ b_gate,
                                              const float* __restrict__ W_cls, const float* __restrict__ b_cls,
                                              float* __restrict__ out) {
    int b = blockIdx.x; int tid = threadIdx.x;
    __shared__ float ssp[HH], ssy[HH], outc[CC];
    for (int j = tid; j < HH; j += blockDim.x) { ssp[j] = span[b * HH + j]; ssy[j] = syn[b * HH + j]; }
    if (tid < CC) outc[tid] = 0.f;
    __syncthreads();
    for (int j = tid; j < HH; j += blockDim.x) {
        float acc = b_gate[j];
        for (int i = 0; i < HH; ++i)
            acc += ssp[i] * W_gate[i * HH + j] + ssy[i] * W_gate[(HH + i) * HH + j];
        float g = 1.0f / (1.0f + __expf(-acc));
        float f = g * ssy[j] + (1.0f - g) * ssp[j];
        for (int c = 0; c < CC; ++c) atomicAdd(&outc[c], f * W_cls[j * CC + c]);
    }
    __syncthreads();
    if (tid < CC) out[b * CC + tid] = b_cls[tid] + outc[tid];
}

extern "C" void kernel_launch(void* const* d_in, const int* in_sizes, int n_in,
                              void* d_out, int out_size, void* d_ws, size_t ws_size,
                              hipStream_t stream) {
    const float* h      = (const float*)d_in[0];
    const int*   eidx   = (const int*)d_in[1];
    const float* ew     = (const float*)d_in[2];
    const int*   ap     = (const int*)d_in[3];
    const float* W_span = (const float*)d_in[4];
    const float* b_span = (const float*)d_in[5];
    const float* W1     = (const float*)d_in[6];
    const float* b1     = (const float*)d_in[7];
    const float* W2     = (const float*)d_in[8];
    const float* b2     = (const float*)d_in[9];
    const float* W_gate = (const float*)d_in[10];
    const float* b_gate = (const float*)d_in[11];
    const float* W_cls  = (const float*)d_in[12];
    const float* b_cls  = (const float*)d_in[13];
    float* out = (float*)d_out;

    float* w    = (float*)d_ws;
    float* deg  = w;                         // B*S
    float* qbuf = deg + BB * SS;             // B*H
    float* part = qbuf + BB * HH;            // B*NB*PSTRIDE
    float* span = part + BB * NB * PSTRIDE;  // B*H
    float* syn  = span + BB * HH;            // B*H

    hipLaunchKernelGGL(k_init, dim3((BB * SS + 255) / 256), dim3(256), 0, stream, deg, syn);
    hipLaunchKernelGGL(k_deg, dim3((BB * EE + 255) / 256), dim3(256), 0, stream, eidx, ew, deg);
    hipLaunchKernelGGL(k_q, dim3(BB), dim3(320), 0, stream, h, ap, W_span, b_span, qbuf);
    hipLaunchKernelGGL(k_span_part, dim3(BB * NB), dim3(256), 0, stream, h, qbuf, part);
    hipLaunchKernelGGL(k_span_final, dim3(BB), dim3(256), 0, stream, part, span);
    hipLaunchKernelGGL(k_syn, dim3(BB * AA), dim3(320), 0, stream, h, eidx, ew, ap, W1, b1, W2, b2, deg, syn);
    hipLaunchKernelGGL(k_head, dim3(BB), dim3(320), 0, stream, span, syn, W_gate, b_gate, W_cls, b_cls, out);
}